// Round 6
// baseline (98.897 us; speedup 1.0000x reference)
//
#include <hip/hip_runtime.h>
#include <math.h>

#define CCH   192
#define RCH   48
#define NB    16
#define HW    9216    // 96*96
#define BCTOT (NB*CCH) // 3072

// ---------------------------------------------------------------------------
// Kernel 1: per-(b,c) plane -> avg, max, 3x3 pooled means
// ---------------------------------------------------------------------------
__global__ __launch_bounds__(256) void k_stats(const float* __restrict__ x,
                                               float* __restrict__ avg,
                                               float* __restrict__ mx,
                                               float* __restrict__ pooled)
{
    int bc = blockIdx.x;
    const float4* p4 = (const float4*)(x + (size_t)bc * HW);
    int t = threadIdx.x;
    float ps[9];
    float m = -INFINITY;
#pragma unroll
    for (int k = 0; k < 9; ++k) {
        int kr = k / 3, kc = k % 3;
        int row = kr * 32 + (t >> 3);
        int wq  = kc * 8  + (t & 7);
        float4 v = p4[row * 24 + wq];
        ps[k] = v.x + v.y + v.z + v.w;
        m = fmaxf(m, fmaxf(fmaxf(v.x, v.y), fmaxf(v.z, v.w)));
    }
#pragma unroll
    for (int off = 32; off > 0; off >>= 1) {
#pragma unroll
        for (int k = 0; k < 9; ++k) ps[k] += __shfl_down(ps[k], off);
        m = fmaxf(m, __shfl_down(m, off));
    }
    __shared__ float red[4][10];
    int wid = t >> 6, lane = t & 63;
    if (lane == 0) {
#pragma unroll
        for (int k = 0; k < 9; ++k) red[wid][k] = ps[k];
        red[wid][9] = m;
    }
    __syncthreads();
    if (t == 0) {
        float tot = 0.f;
#pragma unroll
        for (int k = 0; k < 9; ++k) {
            float pk = red[0][k] + red[1][k] + red[2][k] + red[3][k];
            pooled[bc * 9 + k] = pk * (1.0f / 1024.0f);
            tot += pk;
        }
        float mm = fmaxf(fmaxf(red[0][9], red[1][9]),
                         fmaxf(red[2][9], red[3][9]));
        avg[bc] = tot * (1.0f / (float)HW);
        mx[bc]  = mm;
    }
}

// ---------------------------------------------------------------------------
// Kernel 2 (merged): per-batch theta + h (kept in LDS) + per-(c,k) softmax
// weights. One block per batch.
// ---------------------------------------------------------------------------
__global__ __launch_bounds__(256) void k_coeff(
    const float* __restrict__ avg, const float* __restrict__ mx,
    const float* __restrict__ pooled,
    const float* __restrict__ cam_w1, const float* __restrict__ cam_w2,
    const float* __restrict__ proj_w1,
    const float* __restrict__ bn_gamma, const float* __restrict__ bn_beta,
    const float* __restrict__ proj_w2, const float* __restrict__ adk,
    float* __restrict__ theta, float* __restrict__ wgt)
{
    int b = blockIdx.x;
    int t = threadIdx.x;
    __shared__ float s_av[CCH], s_mx[CCH], s_pool[CCH * 9];
    __shared__ float s_h1p[96], s_h1[RCH], s_hh[RCH * 9];
    if (t < CCH) { s_av[t] = avg[b * CCH + t]; s_mx[t] = mx[b * CCH + t]; }
    for (int i = t; i < CCH * 9; i += 256) s_pool[i] = pooled[b * CCH * 9 + i];
    __syncthreads();
    if (t < 96) {
        int r = t % 48, sel = t / 48;
        const float* src = sel ? s_mx : s_av;
        const float* w = cam_w1 + r * CCH;
        float acc = 0.f;
        for (int c = 0; c < CCH; ++c) acc += src[c] * w[c];
        s_h1p[sel * 48 + r] = fmaxf(acc, 0.f);
    }
    __syncthreads();
    if (t < RCH) s_h1[t] = s_h1p[t] + s_h1p[48 + t];
    __syncthreads();
    if (t < CCH) {
        const float* w = cam_w2 + t * RCH;
        float acc = 0.f;
        for (int r = 0; r < RCH; ++r) acc += s_h1[r] * w[r];
        theta[b * CCH + t] = 1.0f / (1.0f + expf(-acc));
    }
    float bn_s = 1.0f / sqrtf(1.0f + 1e-5f);
    for (int i = t; i < RCH * 9; i += 256) {
        int r = i / 9, k = i % 9;
        const float* w = proj_w1 + r * CCH;
        float acc = 0.f;
        for (int c = 0; c < CCH; ++c) acc += s_pool[c * 9 + k] * w[c];
        float val = acc * (bn_gamma[r] * bn_s) + bn_beta[r];
        s_hh[i] = fmaxf(val, 0.f);
    }
    __syncthreads();
    for (int i = t; i < CCH * 9; i += 256) {
        int c = i / 9, k = i % 9;
        float sg[4];
#pragma unroll
        for (int g = 0; g < 4; ++g) {
            const float* w = proj_w2 + (size_t)(g * CCH + c) * RCH;
            float acc = 0.f;
            for (int r = 0; r < RCH; ++r) acc += s_hh[r * 9 + k] * w[r];
            sg[g] = acc;
        }
        float mxv = fmaxf(fmaxf(sg[0], sg[1]), fmaxf(sg[2], sg[3]));
        float e[4];
        float sum = 0.f;
#pragma unroll
        for (int g = 0; g < 4; ++g) { e[g] = expf(sg[g] - mxv); sum += e[g]; }
        float inv = 1.0f / sum;
        float acc = 0.f;
#pragma unroll
        for (int g = 0; g < 4; ++g)
            acc += (e[g] * inv) * adk[(size_t)(g * CCH + c) * 9 + k];
        wgt[b * CCH * 9 + i] = acc;
    }
}

// ---------------------------------------------------------------------------
// Kernel 3: depthwise 3x3 conv (pad 1). ONE BLOCK PER PLANE, plane staged in
// LDS with a zero halo ring. Layout: sx[(r+1)*100 + c] == x[r][c]; head pad
// s_raw[0..3] serves the (r=-1 via row 0) and the col -1 read of LDS row 0.
// Thread t: rg = t/8 (3 output rows), cs = t%8, owns interleaved f4 columns
// {cs, cs+8, cs+16} so global stores are 128B-contiguous per 8 lanes.
// ---------------------------------------------------------------------------
__global__ __launch_bounds__(256) void k_conv(
    const float* __restrict__ x, const float* __restrict__ wgt,
    const float* __restrict__ theta, float* __restrict__ out)
{
    __shared__ __align__(16) float s_raw[4 + 98 * 100];
    float* sx = s_raw + 4;               // sx[(r+1)*100 + c] = x[r][c]
    float4* sx4 = (float4*)sx;           // 16B-aligned (4-float head pad)

    int plane = blockIdx.x;
    int t = threadIdx.x;

    // ---- zero the halo ring ----
    if (t < 4) s_raw[t] = 0.f;                        // head pad
    if (t < 200) {                                    // LDS rows 0 and 97, full
        int r = t / 100, c = t % 100;
        sx[(r == 0 ? 0 : 97) * 100 + c] = 0.f;
    }
    for (int i = t; i < 384; i += 256) {              // cols 96..99, LDS rows 1..96
        int r = i >> 2, j = i & 3;
        sx[(r + 1) * 100 + 96 + j] = 0.f;
    }

    // ---- stage plane: contiguous global f4 -> LDS ----
    const float4* p4 = (const float4*)(x + (size_t)plane * HW);
#pragma unroll
    for (int i = 0; i < 9; ++i) {
        int i4 = t + i * 256;
        int row = i4 / 24, c4 = i4 % 24;
        sx4[(row + 1) * 25 + c4] = p4[i4];
    }

    // ---- per-plane kernel weights ----
    float wr[9];
    float wsum = 0.f;
#pragma unroll
    for (int k = 0; k < 9; ++k) { wr[k] = wgt[plane * 9 + k]; wsum += wr[k]; }
    float th = theta[plane];
    wr[4] = wr[4] * (1.f + th) - wsum;   // fold theta-center adjustment

    __syncthreads();

    int rg = t >> 3, cs = t & 7;         // rg: 3 output rows, cs: col strip
    float4* o4p = (float4*)(out + (size_t)plane * HW);

    float acc[3][3][4];                  // [out-row][col-block][elem]
#pragma unroll
    for (int i = 0; i < 5; ++i) {
        int lr = 3 * rg + i;             // LDS row index (= data row 3*rg-1+i)
        float w6[3][6];
#pragma unroll
        for (int jb = 0; jb < 3; ++jb) {
            int fc = cs + 8 * jb;                      // f4 column 0..23
            float4 a = sx4[lr * 25 + fc];
            w6[jb][0] = sx[lr * 100 + 4 * fc - 1];     // left halo
            w6[jb][1] = a.x; w6[jb][2] = a.y; w6[jb][3] = a.z; w6[jb][4] = a.w;
            w6[jb][5] = sx[lr * 100 + 4 * fc + 4];     // right halo
        }
        if (i <= 2) {                    // top tap -> init acc[i]
#pragma unroll
            for (int jb = 0; jb < 3; ++jb)
#pragma unroll
                for (int c = 0; c < 4; ++c)
                    acc[i][jb][c] = wr[0] * w6[jb][c] + wr[1] * w6[jb][c + 1] + wr[2] * w6[jb][c + 2];
        }
        if (i >= 1 && i <= 3) {          // mid tap -> acc[i-1]
#pragma unroll
            for (int jb = 0; jb < 3; ++jb)
#pragma unroll
                for (int c = 0; c < 4; ++c)
                    acc[i - 1][jb][c] += wr[3] * w6[jb][c] + wr[4] * w6[jb][c + 1] + wr[5] * w6[jb][c + 2];
        }
        if (i >= 2) {                    // bottom tap -> acc[i-2], store
            const int s = i - 2;
#pragma unroll
            for (int jb = 0; jb < 3; ++jb)
#pragma unroll
                for (int c = 0; c < 4; ++c)
                    acc[s][jb][c] += wr[6] * w6[jb][c] + wr[7] * w6[jb][c + 1] + wr[8] * w6[jb][c + 2];
            int orow = 3 * rg + s;
#pragma unroll
            for (int jb = 0; jb < 3; ++jb)
                o4p[orow * 24 + 8 * jb + cs] =
                    make_float4(acc[s][jb][0], acc[s][jb][1], acc[s][jb][2], acc[s][jb][3]);
        }
    }
}

extern "C" void kernel_launch(void* const* d_in, const int* in_sizes, int n_in,
                              void* d_out, int out_size, void* d_ws, size_t ws_size,
                              hipStream_t stream) {
    const float* x        = (const float*)d_in[0];
    const float* cam_w1   = (const float*)d_in[1];
    const float* cam_w2   = (const float*)d_in[2];
    const float* proj_w1  = (const float*)d_in[3];
    const float* bn_gamma = (const float*)d_in[4];
    const float* bn_beta  = (const float*)d_in[5];
    const float* proj_w2  = (const float*)d_in[6];
    const float* adk      = (const float*)d_in[7];
    float* out = (float*)d_out;
    float* ws  = (float*)d_ws;

    float* avg    = ws;            // 3072
    float* mx     = ws + 3072;     // 3072
    float* pooled = ws + 6144;     // 27648
    float* theta  = ws + 33792;    // 3072
    float* wgt    = ws + 36864;    // 27648

    k_stats <<<BCTOT, 256, 0, stream>>>(x, avg, mx, pooled);
    k_coeff <<<NB,    256, 0, stream>>>(avg, mx, pooled, cam_w1, cam_w2,
                                        proj_w1, bn_gamma, bn_beta,
                                        proj_w2, adk, theta, wgt);
    k_conv  <<<BCTOT, 256, 0, stream>>>(x, wgt, theta, out);
}

// Round 7
// 87.936 us; speedup vs baseline: 1.1247x; 1.1247x over previous
//
#include <hip/hip_runtime.h>
#include <math.h>

#define CCH   192
#define RCH   48
#define NB    16
#define HW    9216    // 96*96
#define BCTOT (NB*CCH) // 3072

typedef float f32x4 __attribute__((ext_vector_type(4)));

__device__ inline void st_nt4(float* p, float a, float b, float c, float d) {
    f32x4 v; v.x = a; v.y = b; v.z = c; v.w = d;
    __builtin_nontemporal_store(v, (f32x4*)p);
}

// ---------------------------------------------------------------------------
// Kernel 1: per-(b,c) plane -> avg, max, 3x3 pooled means.
// 576 threads = 9 waves; wave w owns pooled block (w/3, w%3). Each lane
// privately sums 16 contiguous floats (64B), then ONE wave reduction of
// {sum, max} (12 shfl) instead of 60.
// ---------------------------------------------------------------------------
__global__ __launch_bounds__(576) void k_stats(const float* __restrict__ x,
                                               float* __restrict__ avg,
                                               float* __restrict__ mx,
                                               float* __restrict__ pooled)
{
    int bc = blockIdx.x;
    int t = threadIdx.x;
    int w = t >> 6, l = t & 63;
    int kr = w / 3, kc = w % 3;
    const float4* p4 = (const float4*)(x + (size_t)bc * HW);
    int row = kr * 32 + (l >> 1);
    int c0  = kc * 8 + (l & 1) * 4;
    const float4* pr = p4 + row * 24 + c0;
    float4 v0 = pr[0], v1 = pr[1], v2 = pr[2], v3 = pr[3];
    float s = (v0.x + v0.y + v0.z + v0.w) + (v1.x + v1.y + v1.z + v1.w)
            + (v2.x + v2.y + v2.z + v2.w) + (v3.x + v3.y + v3.z + v3.w);
    float m = fmaxf(fmaxf(fmaxf(v0.x, v0.y), fmaxf(v0.z, v0.w)),
             fmaxf(fmaxf(fmaxf(v1.x, v1.y), fmaxf(v1.z, v1.w)),
             fmaxf(fmaxf(fmaxf(v2.x, v2.y), fmaxf(v2.z, v2.w)),
                   fmaxf(fmaxf(v3.x, v3.y), fmaxf(v3.z, v3.w)))));
#pragma unroll
    for (int off = 32; off > 0; off >>= 1) {
        s += __shfl_down(s, off);
        m = fmaxf(m, __shfl_down(m, off));
    }
    __shared__ float ls[9], lm[9];
    if (l == 0) { ls[w] = s; lm[w] = m; }
    __syncthreads();
    if (t < 9) pooled[bc * 9 + t] = ls[t] * (1.0f / 1024.0f);
    if (t == 0) {
        float tot = 0.f, mm = -INFINITY;
#pragma unroll
        for (int k = 0; k < 9; ++k) { tot += ls[k]; mm = fmaxf(mm, lm[k]); }
        avg[bc] = tot * (1.0f / (float)HW);
        mx[bc]  = mm;
    }
}

// ---------------------------------------------------------------------------
// Kernel 2a: per-batch theta (sigmoid of shared-MLP) + h = relu(bn(proj1(pooled)))
// ---------------------------------------------------------------------------
__global__ __launch_bounds__(256) void k_coeff1(
    const float* __restrict__ avg, const float* __restrict__ mx,
    const float* __restrict__ pooled,
    const float* __restrict__ cam_w1, const float* __restrict__ cam_w2,
    const float* __restrict__ proj_w1,
    const float* __restrict__ bn_gamma, const float* __restrict__ bn_beta,
    float* __restrict__ theta, float* __restrict__ hh)
{
    int b = blockIdx.x;
    int t = threadIdx.x;
    __shared__ float s_av[CCH], s_mx[CCH], s_pool[CCH * 9], s_h1p[96], s_h1[RCH];
    if (t < CCH) { s_av[t] = avg[b * CCH + t]; s_mx[t] = mx[b * CCH + t]; }
    for (int i = t; i < CCH * 9; i += 256) s_pool[i] = pooled[b * CCH * 9 + i];
    __syncthreads();
    if (t < 96) {
        int r = t % 48, sel = t / 48;
        const float* src = sel ? s_mx : s_av;
        const float* w = cam_w1 + r * CCH;
        float acc = 0.f;
        for (int c = 0; c < CCH; ++c) acc += src[c] * w[c];
        s_h1p[sel * 48 + r] = fmaxf(acc, 0.f);
    }
    __syncthreads();
    if (t < RCH) s_h1[t] = s_h1p[t] + s_h1p[48 + t];
    __syncthreads();
    if (t < CCH) {
        const float* w = cam_w2 + t * RCH;
        float acc = 0.f;
        for (int r = 0; r < RCH; ++r) acc += s_h1[r] * w[r];
        theta[b * CCH + t] = 1.0f / (1.0f + expf(-acc));
    }
    float bn_s = 1.0f / sqrtf(1.0f + 1e-5f);
    for (int i = t; i < RCH * 9; i += 256) {
        int r = i / 9, k = i % 9;
        const float* w = proj_w1 + r * CCH;
        float acc = 0.f;
        for (int c = 0; c < CCH; ++c) acc += s_pool[c * 9 + k] * w[c];
        float val = acc * (bn_gamma[r] * bn_s) + bn_beta[r];
        hh[b * RCH * 9 + i] = fmaxf(val, 0.f);
    }
}

// ---------------------------------------------------------------------------
// Kernel 2b: per-(b,c,k) softmax over G=4 groups -> conv weight
// ---------------------------------------------------------------------------
__global__ __launch_bounds__(256) void k_coeff2(
    const float* __restrict__ hh, const float* __restrict__ proj_w2,
    const float* __restrict__ adk, float* __restrict__ wgt)
{
    int gid = blockIdx.x * 256 + threadIdx.x;
    if (gid >= BCTOT * 9) return;
    int b = gid / (CCH * 9);
    int rem = gid % (CCH * 9);
    int c = rem / 9, k = rem % 9;
    const float* hv = hh + b * RCH * 9 + k;
    float sg[4];
#pragma unroll
    for (int g = 0; g < 4; ++g) {
        const float* w = proj_w2 + (size_t)(g * CCH + c) * RCH;
        float acc = 0.f;
        for (int r = 0; r < RCH; ++r) acc += hv[r * 9] * w[r];
        sg[g] = acc;
    }
    float mxv = fmaxf(fmaxf(sg[0], sg[1]), fmaxf(sg[2], sg[3]));
    float e[4];
    float sum = 0.f;
#pragma unroll
    for (int g = 0; g < 4; ++g) { e[g] = expf(sg[g] - mxv); sum += e[g]; }
    float inv = 1.0f / sum;
    float acc = 0.f;
#pragma unroll
    for (int g = 0; g < 4; ++g)
        acc += (e[g] * inv) * adk[(size_t)(g * CCH + c) * 9 + k];
    wgt[gid] = acc;
}

// ---------------------------------------------------------------------------
// Kernel 3: depthwise 3x3 conv (pad 1), vertical sliding window, 8-wide
// strips. Thread: 8 floats (2 f4) x 12 rows; walks 14 input rows once.
// Direct global loads (aligned f4 + 2 edge scalars), NON-TEMPORAL stores so
// out traffic doesn't evict x from L3.
// ---------------------------------------------------------------------------
__global__ __launch_bounds__(256) void k_conv(
    const float* __restrict__ x, const float* __restrict__ wgt,
    const float* __restrict__ theta, float* __restrict__ out)
{
    int gid = blockIdx.x * 256 + threadIdx.x;
    int plane = gid / 96;            // 96 = 8 rowgroups * 12 col-pairs
    int sub   = gid % 96;
    int rg = sub / 12, cp = sub % 12;
    int r0 = rg * 12;

    float wr[9];
    float wsum = 0.f;
#pragma unroll
    for (int k = 0; k < 9; ++k) { wr[k] = wgt[plane * 9 + k]; wsum += wr[k]; }
    float th = theta[plane];
    wr[4] = wr[4] * (1.f + th) - wsum;   // fold theta-center adjustment

    const float* p = x + (size_t)plane * HW;
    const float4* p4 = (const float4*)p;
    float* o = out + (size_t)plane * HW;

    float acc[3][8];
#pragma unroll
    for (int i = 0; i <= 13; ++i) {
        int r = r0 - 1 + i;
        bool inr = (r >= 0) && (r < 96);
        float4 a, b;
        float lh, rh;
        if (inr) {
            const float4* pr = p4 + r * 24 + 2 * cp;
            a = pr[0]; b = pr[1];
            lh = (cp > 0)  ? p[r * 96 + 8 * cp - 1] : 0.f;
            rh = (cp < 11) ? p[r * 96 + 8 * cp + 8] : 0.f;
        } else {
            a = make_float4(0.f, 0.f, 0.f, 0.f);
            b = a; lh = 0.f; rh = 0.f;
        }
        float win[10];
        win[0] = lh;
        win[1] = a.x; win[2] = a.y; win[3] = a.z; win[4] = a.w;
        win[5] = b.x; win[6] = b.y; win[7] = b.z; win[8] = b.w;
        win[9] = rh;

        if (i <= 11) {
#pragma unroll
            for (int j = 0; j < 8; ++j)
                acc[i % 3][j] = wr[0] * win[j] + wr[1] * win[j + 1] + wr[2] * win[j + 2];
        }
        if (i >= 1 && i <= 12) {
#pragma unroll
            for (int j = 0; j < 8; ++j)
                acc[(i - 1) % 3][j] += wr[3] * win[j] + wr[4] * win[j + 1] + wr[5] * win[j + 2];
        }
        if (i >= 2) {
            const int s = (i - 2) % 3;
#pragma unroll
            for (int j = 0; j < 8; ++j)
                acc[s][j] += wr[6] * win[j] + wr[7] * win[j + 1] + wr[8] * win[j + 2];
            int orow = r0 + i - 2;
            float* od = o + orow * 96 + 8 * cp;
            st_nt4(od,     acc[s][0], acc[s][1], acc[s][2], acc[s][3]);
            st_nt4(od + 4, acc[s][4], acc[s][5], acc[s][6], acc[s][7]);
        }
    }
}

extern "C" void kernel_launch(void* const* d_in, const int* in_sizes, int n_in,
                              void* d_out, int out_size, void* d_ws, size_t ws_size,
                              hipStream_t stream) {
    const float* x        = (const float*)d_in[0];
    const float* cam_w1   = (const float*)d_in[1];
    const float* cam_w2   = (const float*)d_in[2];
    const float* proj_w1  = (const float*)d_in[3];
    const float* bn_gamma = (const float*)d_in[4];
    const float* bn_beta  = (const float*)d_in[5];
    const float* proj_w2  = (const float*)d_in[6];
    const float* adk      = (const float*)d_in[7];
    float* out = (float*)d_out;
    float* ws  = (float*)d_ws;

    float* avg    = ws;            // 3072
    float* mx     = ws + 3072;     // 3072
    float* pooled = ws + 6144;     // 27648
    float* theta  = ws + 33792;    // 3072
    float* hh     = ws + 36864;    // 6912
    float* wgt    = ws + 43776;    // 27648

    k_stats  <<<BCTOT, 576, 0, stream>>>(x, avg, mx, pooled);
    k_coeff1 <<<NB,    256, 0, stream>>>(avg, mx, pooled, cam_w1, cam_w2,
                                         proj_w1, bn_gamma, bn_beta, theta, hh);
    k_coeff2 <<<(BCTOT * 9) / 256, 256, 0, stream>>>(hh, proj_w2, adk, wgt);
    k_conv   <<<(BCTOT * 96) / 256, 256, 0, stream>>>(x, wgt, theta, out);
}

// Round 8
// 83.920 us; speedup vs baseline: 1.1785x; 1.0478x over previous
//
#include <hip/hip_runtime.h>
#include <math.h>

#define CCH   192
#define RCH   48
#define NB    16
#define HW    9216    // 96*96
#define BCTOT (NB*CCH) // 3072

// ---------------------------------------------------------------------------
// Kernel 1: per-(b,c) plane -> avg, max, 3x3 pooled means.
// 576 threads = 9 waves; wave w owns pooled block (w/3, w%3). Each lane
// privately sums 16 contiguous floats (64B), then ONE wave reduction of
// {sum, max} (12 shfl).
// ---------------------------------------------------------------------------
__global__ __launch_bounds__(576) void k_stats(const float* __restrict__ x,
                                               float* __restrict__ avg,
                                               float* __restrict__ mx,
                                               float* __restrict__ pooled)
{
    int bc = blockIdx.x;
    int t = threadIdx.x;
    int w = t >> 6, l = t & 63;
    int kr = w / 3, kc = w % 3;
    const float4* p4 = (const float4*)(x + (size_t)bc * HW);
    int row = kr * 32 + (l >> 1);
    int c0  = kc * 8 + (l & 1) * 4;
    const float4* pr = p4 + row * 24 + c0;
    float4 v0 = pr[0], v1 = pr[1], v2 = pr[2], v3 = pr[3];
    float s = (v0.x + v0.y + v0.z + v0.w) + (v1.x + v1.y + v1.z + v1.w)
            + (v2.x + v2.y + v2.z + v2.w) + (v3.x + v3.y + v3.z + v3.w);
    float m = fmaxf(fmaxf(fmaxf(v0.x, v0.y), fmaxf(v0.z, v0.w)),
             fmaxf(fmaxf(fmaxf(v1.x, v1.y), fmaxf(v1.z, v1.w)),
             fmaxf(fmaxf(fmaxf(v2.x, v2.y), fmaxf(v2.z, v2.w)),
                   fmaxf(fmaxf(v3.x, v3.y), fmaxf(v3.z, v3.w)))));
#pragma unroll
    for (int off = 32; off > 0; off >>= 1) {
        s += __shfl_down(s, off);
        m = fmaxf(m, __shfl_down(m, off));
    }
    __shared__ float ls[9], lm[9];
    if (l == 0) { ls[w] = s; lm[w] = m; }
    __syncthreads();
    if (t < 9) pooled[bc * 9 + t] = ls[t] * (1.0f / 1024.0f);
    if (t == 0) {
        float tot = 0.f, mm = -INFINITY;
#pragma unroll
        for (int k = 0; k < 9; ++k) { tot += ls[k]; mm = fmaxf(mm, lm[k]); }
        avg[bc] = tot * (1.0f / (float)HW);
        mx[bc]  = mm;
    }
}

// ---------------------------------------------------------------------------
// Kernel 2a: per-batch theta + h = relu(bn(proj1(pooled)))
// ---------------------------------------------------------------------------
__global__ __launch_bounds__(256) void k_coeff1(
    const float* __restrict__ avg, const float* __restrict__ mx,
    const float* __restrict__ pooled,
    const float* __restrict__ cam_w1, const float* __restrict__ cam_w2,
    const float* __restrict__ proj_w1,
    const float* __restrict__ bn_gamma, const float* __restrict__ bn_beta,
    float* __restrict__ theta, float* __restrict__ hh)
{
    int b = blockIdx.x;
    int t = threadIdx.x;
    __shared__ float s_av[CCH], s_mx[CCH], s_pool[CCH * 9], s_h1p[96], s_h1[RCH];
    if (t < CCH) { s_av[t] = avg[b * CCH + t]; s_mx[t] = mx[b * CCH + t]; }
    for (int i = t; i < CCH * 9; i += 256) s_pool[i] = pooled[b * CCH * 9 + i];
    __syncthreads();
    if (t < 96) {
        int r = t % 48, sel = t / 48;
        const float* src = sel ? s_mx : s_av;
        const float* w = cam_w1 + r * CCH;
        float acc = 0.f;
        for (int c = 0; c < CCH; ++c) acc += src[c] * w[c];
        s_h1p[sel * 48 + r] = fmaxf(acc, 0.f);
    }
    __syncthreads();
    if (t < RCH) s_h1[t] = s_h1p[t] + s_h1p[48 + t];
    __syncthreads();
    if (t < CCH) {
        const float* w = cam_w2 + t * RCH;
        float acc = 0.f;
        for (int r = 0; r < RCH; ++r) acc += s_h1[r] * w[r];
        theta[b * CCH + t] = 1.0f / (1.0f + expf(-acc));
    }
    float bn_s = 1.0f / sqrtf(1.0f + 1e-5f);
    for (int i = t; i < RCH * 9; i += 256) {
        int r = i / 9, k = i % 9;
        const float* w = proj_w1 + r * CCH;
        float acc = 0.f;
        for (int c = 0; c < CCH; ++c) acc += s_pool[c * 9 + k] * w[c];
        float val = acc * (bn_gamma[r] * bn_s) + bn_beta[r];
        hh[b * RCH * 9 + i] = fmaxf(val, 0.f);
    }
}

// ---------------------------------------------------------------------------
// Kernel 2b: per-(b,c,k) softmax over G=4 groups -> conv weight
// ---------------------------------------------------------------------------
__global__ __launch_bounds__(256) void k_coeff2(
    const float* __restrict__ hh, const float* __restrict__ proj_w2,
    const float* __restrict__ adk, float* __restrict__ wgt)
{
    int gid = blockIdx.x * 256 + threadIdx.x;
    if (gid >= BCTOT * 9) return;
    int b = gid / (CCH * 9);
    int rem = gid % (CCH * 9);
    int c = rem / 9, k = rem % 9;
    const float* hv = hh + b * RCH * 9 + k;
    float sg[4];
#pragma unroll
    for (int g = 0; g < 4; ++g) {
        const float* w = proj_w2 + (size_t)(g * CCH + c) * RCH;
        float acc = 0.f;
        for (int r = 0; r < RCH; ++r) acc += hv[r * 9] * w[r];
        sg[g] = acc;
    }
    float mxv = fmaxf(fmaxf(sg[0], sg[1]), fmaxf(sg[2], sg[3]));
    float e[4];
    float sum = 0.f;
#pragma unroll
    for (int g = 0; g < 4; ++g) { e[g] = expf(sg[g] - mxv); sum += e[g]; }
    float inv = 1.0f / sum;
    float acc = 0.f;
#pragma unroll
    for (int g = 0; g < 4; ++g)
        acc += (e[g] * inv) * adk[(size_t)(g * CCH + c) * 9 + k];
    wgt[gid] = acc;
}

// ---------------------------------------------------------------------------
// Kernel 3: depthwise 3x3 conv (pad 1), vertical sliding window (R2-exact).
// Thread: 4-wide x 12-row output strip; walks 14 input rows once,
// 3 rotating accumulators (all indices compile-time via full unroll).
// ---------------------------------------------------------------------------
__global__ __launch_bounds__(256) void k_conv(
    const float* __restrict__ x, const float* __restrict__ wgt,
    const float* __restrict__ theta, float* __restrict__ out)
{
    int gid = blockIdx.x * 256 + threadIdx.x;
    int plane = gid / 192;          // 192 = 8 rowgroups * 24 wq
    int sub   = gid % 192;
    int rg = sub / 24, wq = sub % 24;
    int r0 = rg * 12;
    int w0 = wq * 4;

    float wr[9];
    float wsum = 0.f;
#pragma unroll
    for (int k = 0; k < 9; ++k) { wr[k] = wgt[plane * 9 + k]; wsum += wr[k]; }
    float th = theta[plane];
    wr[4] = wr[4] * (1.f + th) - wsum;   // fold theta-center adjustment

    const float* p = x + (size_t)plane * HW;
    float* o = out + (size_t)plane * HW;

    float acc[3][4];
#pragma unroll
    for (int i = 0; i <= 13; ++i) {
        int r = r0 - 1 + i;
        float win[6];
        bool inr = (r >= 0) && (r < 96);
        const float* prow = p + r * 96;
        if (inr) {
            float4 a = ((const float4*)prow)[wq];
            win[0] = (wq > 0)  ? prow[w0 - 1] : 0.f;
            win[1] = a.x; win[2] = a.y; win[3] = a.z; win[4] = a.w;
            win[5] = (wq < 23) ? prow[w0 + 4] : 0.f;
        } else {
#pragma unroll
            for (int j = 0; j < 6; ++j) win[j] = 0.f;
        }
        if (i <= 11) {
#pragma unroll
            for (int j = 0; j < 4; ++j)
                acc[i % 3][j] = wr[0] * win[j] + wr[1] * win[j + 1] + wr[2] * win[j + 2];
        }
        if (i >= 1 && i <= 12) {
#pragma unroll
            for (int j = 0; j < 4; ++j)
                acc[(i - 1) % 3][j] += wr[3] * win[j] + wr[4] * win[j + 1] + wr[5] * win[j + 2];
        }
        if (i >= 2) {
            const int s = (i - 2) % 3;
#pragma unroll
            for (int j = 0; j < 4; ++j)
                acc[s][j] += wr[6] * win[j] + wr[7] * win[j + 1] + wr[8] * win[j + 2];
            float4 o4;
            o4.x = acc[s][0]; o4.y = acc[s][1]; o4.z = acc[s][2]; o4.w = acc[s][3];
            ((float4*)(o + (size_t)(r - 1) * 96))[wq] = o4;
        }
    }
}

extern "C" void kernel_launch(void* const* d_in, const int* in_sizes, int n_in,
                              void* d_out, int out_size, void* d_ws, size_t ws_size,
                              hipStream_t stream) {
    const float* x        = (const float*)d_in[0];
    const float* cam_w1   = (const float*)d_in[1];
    const float* cam_w2   = (const float*)d_in[2];
    const float* proj_w1  = (const float*)d_in[3];
    const float* bn_gamma = (const float*)d_in[4];
    const float* bn_beta  = (const float*)d_in[5];
    const float* proj_w2  = (const float*)d_in[6];
    const float* adk      = (const float*)d_in[7];
    float* out = (float*)d_out;
    float* ws  = (float*)d_ws;

    float* avg    = ws;            // 3072
    float* mx     = ws + 3072;     // 3072
    float* pooled = ws + 6144;     // 27648
    float* theta  = ws + 33792;    // 3072
    float* hh     = ws + 36864;    // 6912
    float* wgt    = ws + 43776;    // 27648

    k_stats  <<<BCTOT, 576, 0, stream>>>(x, avg, mx, pooled);
    k_coeff1 <<<NB,    256, 0, stream>>>(avg, mx, pooled, cam_w1, cam_w2,
                                         proj_w1, bn_gamma, bn_beta, theta, hh);
    k_coeff2 <<<(BCTOT * 9) / 256, 256, 0, stream>>>(hh, proj_w2, adk, wgt);
    k_conv   <<<(BCTOT * 192) / 256, 256, 0, stream>>>(x, wgt, theta, out);
}

// Round 10
// 83.918 us; speedup vs baseline: 1.1785x; 1.0000x over previous
//
#include <hip/hip_runtime.h>
#include <math.h>

#define CCH   192
#define RCH   48
#define NB    16
#define HW    9216    // 96*96
#define BCTOT (NB*CCH) // 3072

// ---------------------------------------------------------------------------
// Kernel 1: ONE WAVE per pooled 32x32 block. No LDS, no barriers, no block
// tail. Lane reads 64B contiguous (4 f4); 12-shfl wave reduce; lane 0 writes
// pooled mean + block max. avg/mx are finished in k_coeff1 from these.
// Grid: 6912 blocks x 4 waves = 27648 waves = BCTOT*9.
// ---------------------------------------------------------------------------
__global__ __launch_bounds__(256) void k_stats(const float* __restrict__ x,
                                               float* __restrict__ pooled,
                                               float* __restrict__ wmax)
{
    int t = threadIdx.x;
    int g = blockIdx.x * 4 + (t >> 6);     // global wave id, 0..27647
    int l = t & 63;
    int bc = g / 9, k = g % 9;
    int kr = k / 3, kc = k % 3;
    const float4* p4 = (const float4*)(x + (size_t)bc * HW);
    int row = kr * 32 + (l >> 1);
    int c0  = kc * 8 + (l & 1) * 4;
    const float4* pr = p4 + row * 24 + c0;
    float4 v0 = pr[0], v1 = pr[1], v2 = pr[2], v3 = pr[3];
    float s = (v0.x + v0.y + v0.z + v0.w) + (v1.x + v1.y + v1.z + v1.w)
            + (v2.x + v2.y + v2.z + v2.w) + (v3.x + v3.y + v3.z + v3.w);
    float m = fmaxf(fmaxf(fmaxf(v0.x, v0.y), fmaxf(v0.z, v0.w)),
             fmaxf(fmaxf(fmaxf(v1.x, v1.y), fmaxf(v1.z, v1.w)),
             fmaxf(fmaxf(fmaxf(v2.x, v2.y), fmaxf(v2.z, v2.w)),
                   fmaxf(fmaxf(v3.x, v3.y), fmaxf(v3.z, v3.w)))));
#pragma unroll
    for (int off = 32; off > 0; off >>= 1) {
        s += __shfl_down(s, off);
        m = fmaxf(m, __shfl_down(m, off));
    }
    if (l == 0) {
        pooled[g] = s * (1.0f / 1024.0f);
        wmax[g]   = m;
    }
}

// ---------------------------------------------------------------------------
// Kernel 2a: per-batch theta + h = relu(bn(proj1(pooled))).
// Finishes avg (= mean of 9 pooled) and mx (= max of 9 wmax) in LDS.
// ---------------------------------------------------------------------------
__global__ __launch_bounds__(256) void k_coeff1(
    const float* __restrict__ pooled, const float* __restrict__ wmax,
    const float* __restrict__ cam_w1, const float* __restrict__ cam_w2,
    const float* __restrict__ proj_w1,
    const float* __restrict__ bn_gamma, const float* __restrict__ bn_beta,
    float* __restrict__ theta, float* __restrict__ hh)
{
    int b = blockIdx.x;
    int t = threadIdx.x;
    __shared__ float s_av[CCH], s_mx[CCH], s_pool[CCH * 9], s_wm[CCH * 9];
    __shared__ float s_h1p[96], s_h1[RCH];
    for (int i = t; i < CCH * 9; i += 256) {
        s_pool[i] = pooled[b * CCH * 9 + i];
        s_wm[i]   = wmax[b * CCH * 9 + i];
    }
    __syncthreads();
    if (t < CCH) {
        float sa = 0.f, sm = -INFINITY;
#pragma unroll
        for (int k = 0; k < 9; ++k) {
            sa += s_pool[t * 9 + k];
            sm = fmaxf(sm, s_wm[t * 9 + k]);
        }
        s_av[t] = sa * (1.0f / 9.0f);
        s_mx[t] = sm;
    }
    __syncthreads();
    if (t < 96) {
        int r = t % 48, sel = t / 48;
        const float* src = sel ? s_mx : s_av;
        const float* w = cam_w1 + r * CCH;
        float acc = 0.f;
        for (int c = 0; c < CCH; ++c) acc += src[c] * w[c];
        s_h1p[sel * 48 + r] = fmaxf(acc, 0.f);
    }
    __syncthreads();
    if (t < RCH) s_h1[t] = s_h1p[t] + s_h1p[48 + t];
    __syncthreads();
    if (t < CCH) {
        const float* w = cam_w2 + t * RCH;
        float acc = 0.f;
        for (int r = 0; r < RCH; ++r) acc += s_h1[r] * w[r];
        theta[b * CCH + t] = 1.0f / (1.0f + expf(-acc));
    }
    float bn_s = 1.0f / sqrtf(1.0f + 1e-5f);
    for (int i = t; i < RCH * 9; i += 256) {
        int r = i / 9, k = i % 9;
        const float* w = proj_w1 + r * CCH;
        float acc = 0.f;
        for (int c = 0; c < CCH; ++c) acc += s_pool[c * 9 + k] * w[c];
        float val = acc * (bn_gamma[r] * bn_s) + bn_beta[r];
        hh[b * RCH * 9 + i] = fmaxf(val, 0.f);
    }
}

// ---------------------------------------------------------------------------
// Kernel 2b: per-(b,c,k) softmax over G=4 groups -> conv weight
// ---------------------------------------------------------------------------
__global__ __launch_bounds__(256) void k_coeff2(
    const float* __restrict__ hh, const float* __restrict__ proj_w2,
    const float* __restrict__ adk, float* __restrict__ wgt)
{
    int gid = blockIdx.x * 256 + threadIdx.x;
    if (gid >= BCTOT * 9) return;
    int b = gid / (CCH * 9);
    int rem = gid % (CCH * 9);
    int c = rem / 9, k = rem % 9;
    const float* hv = hh + b * RCH * 9 + k;
    float sg[4];
#pragma unroll
    for (int g = 0; g < 4; ++g) {
        const float* w = proj_w2 + (size_t)(g * CCH + c) * RCH;
        float acc = 0.f;
        for (int r = 0; r < RCH; ++r) acc += hv[r * 9] * w[r];
        sg[g] = acc;
    }
    float mxv = fmaxf(fmaxf(sg[0], sg[1]), fmaxf(sg[2], sg[3]));
    float e[4];
    float sum = 0.f;
#pragma unroll
    for (int g = 0; g < 4; ++g) { e[g] = expf(sg[g] - mxv); sum += e[g]; }
    float inv = 1.0f / sum;
    float acc = 0.f;
#pragma unroll
    for (int g = 0; g < 4; ++g)
        acc += (e[g] * inv) * adk[(size_t)(g * CCH + c) * 9 + k];
    wgt[gid] = acc;
}

// ---------------------------------------------------------------------------
// Kernel 3: depthwise 3x3 conv (pad 1), vertical sliding window (R2-exact).
// Thread: 4-wide x 12-row output strip; walks 14 input rows once,
// 3 rotating accumulators (all indices compile-time via full unroll).
// ---------------------------------------------------------------------------
__global__ __launch_bounds__(256) void k_conv(
    const float* __restrict__ x, const float* __restrict__ wgt,
    const float* __restrict__ theta, float* __restrict__ out)
{
    int gid = blockIdx.x * 256 + threadIdx.x;
    int plane = gid / 192;          // 192 = 8 rowgroups * 24 wq
    int sub   = gid % 192;
    int rg = sub / 24, wq = sub % 24;
    int r0 = rg * 12;
    int w0 = wq * 4;

    float wr[9];
    float wsum = 0.f;
#pragma unroll
    for (int k = 0; k < 9; ++k) { wr[k] = wgt[plane * 9 + k]; wsum += wr[k]; }
    float th = theta[plane];
    wr[4] = wr[4] * (1.f + th) - wsum;   // fold theta-center adjustment

    const float* p = x + (size_t)plane * HW;
    float* o = out + (size_t)plane * HW;

    float acc[3][4];
#pragma unroll
    for (int i = 0; i <= 13; ++i) {
        int r = r0 - 1 + i;
        float win[6];
        bool inr = (r >= 0) && (r < 96);
        const float* prow = p + r * 96;
        if (inr) {
            float4 a = ((const float4*)prow)[wq];
            win[0] = (wq > 0)  ? prow[w0 - 1] : 0.f;
            win[1] = a.x; win[2] = a.y; win[3] = a.z; win[4] = a.w;
            win[5] = (wq < 23) ? prow[w0 + 4] : 0.f;
        } else {
#pragma unroll
            for (int j = 0; j < 6; ++j) win[j] = 0.f;
        }
        if (i <= 11) {
#pragma unroll
            for (int j = 0; j < 4; ++j)
                acc[i % 3][j] = wr[0] * win[j] + wr[1] * win[j + 1] + wr[2] * win[j + 2];
        }
        if (i >= 1 && i <= 12) {
#pragma unroll
            for (int j = 0; j < 4; ++j)
                acc[(i - 1) % 3][j] += wr[3] * win[j] + wr[4] * win[j + 1] + wr[5] * win[j + 2];
        }
        if (i >= 2) {
            const int s = (i - 2) % 3;
#pragma unroll
            for (int j = 0; j < 4; ++j)
                acc[s][j] += wr[6] * win[j] + wr[7] * win[j + 1] + wr[8] * win[j + 2];
            float4 o4;
            o4.x = acc[s][0]; o4.y = acc[s][1]; o4.z = acc[s][2]; o4.w = acc[s][3];
            ((float4*)(o + (size_t)(r - 1) * 96))[wq] = o4;
        }
    }
}

extern "C" void kernel_launch(void* const* d_in, const int* in_sizes, int n_in,
                              void* d_out, int out_size, void* d_ws, size_t ws_size,
                              hipStream_t stream) {
    const float* x        = (const float*)d_in[0];
    const float* cam_w1   = (const float*)d_in[1];
    const float* cam_w2   = (const float*)d_in[2];
    const float* proj_w1  = (const float*)d_in[3];
    const float* bn_gamma = (const float*)d_in[4];
    const float* bn_beta  = (const float*)d_in[5];
    const float* proj_w2  = (const float*)d_in[6];
    const float* adk      = (const float*)d_in[7];
    float* out = (float*)d_out;
    float* ws  = (float*)d_ws;

    float* pooled = ws;            // 27648
    float* wmaxg  = ws + 27648;    // 27648 (aliased: wgt after coeff1 consumes)
    float* theta  = ws + 55296;    // 3072
    float* hh     = ws + 58368;    // 6912
    float* wgt    = wmaxg;         // alias — wmax dead after k_coeff1

    k_stats  <<<(BCTOT * 9) / 4, 256, 0, stream>>>(x, pooled, wmaxg);   // 6912 blocks
    k_coeff1 <<<NB, 256, 0, stream>>>(pooled, wmaxg, cam_w1, cam_w2,
                                      proj_w1, bn_gamma, bn_beta, theta, hh);
    k_coeff2 <<<(BCTOT * 9) / 256, 256, 0, stream>>>(hh, proj_w2, adk, wgt);
    k_conv   <<<(BCTOT * 192) / 256, 256, 0, stream>>>(x, wgt, theta, out);
}